// Round 1
// baseline (124.065 us; speedup 1.0000x reference)
//
#include <hip/hip_runtime.h>

// PatchMask: out[b,c,t] = x[b,c,t] * unit_mask[c*NP + t/PATCH]
// B=128, C=128, T=5000, PATCH=25, NP=200, UNITS=25600, NMASK=2560

#define PM_B 128
#define PM_C 128
#define PM_T 5000
#define PM_PATCH 25
#define PM_NP 200           // PM_T / PM_PATCH
#define PM_UNITS (PM_C * PM_NP)   // 25600
#define PM_NMASK 2560

__global__ void pm_init_mask(float* __restrict__ um) {
    int i = blockIdx.x * blockDim.x + threadIdx.x;
    if (i < PM_UNITS) um[i] = 1.0f;
}

__global__ void pm_scatter_mask(const int* __restrict__ idx, float* __restrict__ um) {
    int i = blockIdx.x * blockDim.x + threadIdx.x;
    if (i < PM_NMASK) um[idx[i]] = 0.0f;
}

__global__ __launch_bounds__(256) void pm_apply_mask(
    const float* __restrict__ x,
    const float* __restrict__ um,
    float* __restrict__ out)
{
    const int c  = blockIdx.y;
    const int b  = blockIdx.z;
    const int t0 = (blockIdx.x * blockDim.x + threadIdx.x) * 4;
    if (t0 >= PM_T) return;   // 5 blocks * 256 * 4 = 5120 > 5000; 5000 % 4 == 0 so full-vec guard is safe

    const float* __restrict__ um_c = um + c * PM_NP;
    const size_t base = ((size_t)b * PM_C + c) * PM_T + t0;

    float4 v = *reinterpret_cast<const float4*>(x + base);

    const int p0 = t0 / PM_PATCH;
    const int p3 = (t0 + 3) / PM_PATCH;
    const float m0 = um_c[p0];
    if (p0 == p3) {
        v.x *= m0; v.y *= m0; v.z *= m0; v.w *= m0;
    } else {
        const float m3 = um_c[p3];
        const int boundary = p3 * PM_PATCH;  // first t belonging to patch p3
        v.x *= (t0 + 0 < boundary) ? m0 : m3;
        v.y *= (t0 + 1 < boundary) ? m0 : m3;
        v.z *= (t0 + 2 < boundary) ? m0 : m3;
        v.w *= (t0 + 3 < boundary) ? m0 : m3;
    }

    *reinterpret_cast<float4*>(out + base) = v;
}

extern "C" void kernel_launch(void* const* d_in, const int* in_sizes, int n_in,
                              void* d_out, int out_size, void* d_ws, size_t ws_size,
                              hipStream_t stream) {
    const float* x   = (const float*)d_in[0];
    const int*   idx = (const int*)d_in[1];
    float*       out = (float*)d_out;
    float*       um  = (float*)d_ws;   // 25600 floats = 100 KiB scratch

    pm_init_mask<<<(PM_UNITS + 255) / 256, 256, 0, stream>>>(um);
    pm_scatter_mask<<<(PM_NMASK + 255) / 256, 256, 0, stream>>>(idx, um);

    dim3 grid((PM_T / 4 + 255) / 256, PM_C, PM_B);  // (5, 128, 128)
    pm_apply_mask<<<grid, 256, 0, stream>>>(x, um, out);
}

// Round 3
// 121.804 us; speedup vs baseline: 1.0186x; 1.0186x over previous
//
#include <hip/hip_runtime.h>

// PatchMask: out[b,c,t] = x[b,c,t] * (1 - masked[c*NP + t/PATCH])
// B=128, C=128, T=5000, PATCH=25, NP=200, UNITS=25600, NMASK=2560
// Flag encoding: um[] is 0.0 by default (memset node), 1.0 at masked units.

#define PM_B 128
#define PM_C 128
#define PM_T 5000
#define PM_PATCH 25
#define PM_NP 200                      // PM_T / PM_PATCH
#define PM_UNITS (PM_C * PM_NP)        // 25600
#define PM_NMASK 2560
#define PM_F4_PER_ROW (PM_T / 4)       // 1250
#define PM_F4_TOTAL (PM_B * PM_C * PM_F4_PER_ROW)  // 20,480,000

typedef float f32x4 __attribute__((ext_vector_type(4)));  // native vector: OK for nontemporal builtins

__global__ void pm_scatter_mask(const int* __restrict__ idx, float* __restrict__ um) {
    int i = blockIdx.x * blockDim.x + threadIdx.x;
    if (i < PM_NMASK) um[idx[i]] = 1.0f;   // flag = masked
}

__global__ __launch_bounds__(256) void pm_apply_mask(
    const f32x4* __restrict__ x,
    const float* __restrict__ um,
    f32x4* __restrict__ out)
{
    unsigned i = blockIdx.x * 256u + threadIdx.x;
    const unsigned stride = gridDim.x * 256u;
    for (; i < PM_F4_TOTAL; i += stride) {
        const unsigned row = i / PM_F4_PER_ROW;          // b*C + c  (magic-mul)
        const unsigned t0  = (i - row * PM_F4_PER_ROW) * 4u;
        const float* __restrict__ um_c = um + (row & (PM_C - 1)) * PM_NP;

        f32x4 v = __builtin_nontemporal_load(x + i);

        const unsigned p0 = t0 / PM_PATCH;
        const unsigned p3 = (t0 + 3u) / PM_PATCH;
        const float m0 = 1.0f - um_c[p0];
        if (p0 == p3) {
            v *= m0;
        } else {
            const float m3 = 1.0f - um_c[p3];
            const unsigned boundary = p3 * PM_PATCH;     // first t in patch p3
            v.x *= (t0 + 0u < boundary) ? m0 : m3;
            v.y *= (t0 + 1u < boundary) ? m0 : m3;
            v.z *= (t0 + 2u < boundary) ? m0 : m3;
            v.w *= (t0 + 3u < boundary) ? m0 : m3;
        }

        __builtin_nontemporal_store(v, out + i);
    }
}

extern "C" void kernel_launch(void* const* d_in, const int* in_sizes, int n_in,
                              void* d_out, int out_size, void* d_ws, size_t ws_size,
                              hipStream_t stream) {
    const float* x   = (const float*)d_in[0];
    const int*   idx = (const int*)d_in[1];
    float*       out = (float*)d_out;
    float*       um  = (float*)d_ws;   // 25600 floats = 100 KiB scratch

    // mask = 0 everywhere (memset node — graph-capturable), then 1.0 at masked
    (void)hipMemsetAsync(um, 0, PM_UNITS * sizeof(float), stream);
    pm_scatter_mask<<<(PM_NMASK + 255) / 256, 256, 0, stream>>>(idx, um);

    // 2048 blocks x 256 threads = 32 waves/CU on 256 CUs; grid-stride the rest
    pm_apply_mask<<<2048, 256, 0, stream>>>(
        (const f32x4*)x, um, (f32x4*)out);
}